// Round 4
// baseline (682.750 us; speedup 1.0000x reference)
//
#include <hip/hip_runtime.h>
#include <hip/hip_bf16.h>

// GlobalAttention (general): B=32, T=512, S=1024, D=1024, f32 in/out.
// Split-bf16 (hi+lo) MFMA GEMMs using v_mfma_f32_32x32x16_bf16 (2x FLOP per
// LDS byte vs 16x16x32 -> MFMA-bound phases). 256x256 tile, BK=32, 2 k-half
// phases/tile. XOR-swizzled LDS (phys_blk = logical ^ ((row>>1)&3), 64B rows)
// via pre-swizzled global source + swizzled ds_read addr. All tile t+1 staging
// issued in t.ph0; one vmcnt(0)/tile at ph1 tail (landed by then).

typedef short bf16x8 __attribute__((ext_vector_type(8)));
typedef float f32x16 __attribute__((ext_vector_type(16)));
typedef unsigned short us;

#define NB 32
#define NT_ 512
#define NS 1024
#define ND 1024

__device__ inline us f2bf(float x) {
  unsigned u = __float_as_uint(x);
  u += 0x7FFFu + ((u >> 16) & 1u);
  return (us)(u >> 16);
}
__device__ inline float bf2f(us h) { return __uint_as_float(((unsigned)h) << 16); }

__device__ inline void store_split(us* __restrict__ hi, us* __restrict__ lo, size_t idx, float v) {
  us h = f2bf(v);
  hi[idx] = h;
  lo[idx] = f2bf(v - bf2f(h));
}

// ---------------- elementwise split / convert ----------------
__global__ void ga_split(const float* __restrict__ src, us* __restrict__ hi,
                         us* __restrict__ lo, long n) {
  long i0 = ((long)blockIdx.x * blockDim.x + threadIdx.x) * 4;
  long stride = (long)gridDim.x * blockDim.x * 4;
  for (long i = i0; i < n; i += stride) {
    float4 v = *reinterpret_cast<const float4*>(src + i);
    ushort4 h, l;
    h.x = f2bf(v.x); l.x = f2bf(v.x - bf2f(h.x));
    h.y = f2bf(v.y); l.y = f2bf(v.y - bf2f(h.y));
    h.z = f2bf(v.z); l.z = f2bf(v.z - bf2f(h.z));
    h.w = f2bf(v.w); l.w = f2bf(v.w - bf2f(h.w));
    *reinterpret_cast<ushort4*>(hi + i) = h;
    *reinterpret_cast<ushort4*>(lo + i) = l;
  }
}

__global__ void ga_cvt(const float* __restrict__ src, us* __restrict__ dst, long n) {
  long i0 = ((long)blockIdx.x * blockDim.x + threadIdx.x) * 4;
  long stride = (long)gridDim.x * blockDim.x * 4;
  for (long i = i0; i < n; i += stride) {
    float4 v = *reinterpret_cast<const float4*>(src + i);
    ushort4 h;
    h.x = f2bf(v.x); h.y = f2bf(v.y); h.z = f2bf(v.z); h.w = f2bf(v.w);
    *reinterpret_cast<ushort4*>(dst + i) = h;
  }
}

// ---------------- ctx transpose+split: [B][S][D] f32 -> [B][D][S] bf16 hi/lo ----------------
__global__ void ga_transpose_split(const float* __restrict__ ctx, us* __restrict__ tHi,
                                   us* __restrict__ tLo) {
  __shared__ float tile[64][65];
  int s0 = blockIdx.x << 6, d0 = blockIdx.y << 6, b = blockIdx.z;
  const float* src = ctx + (size_t)b * NS * ND;
  int tid = threadIdx.x;
#pragma unroll
  for (int i = 0; i < 16; ++i) {
    int lin = (i << 8) + tid;
    int r = lin >> 6, c = lin & 63;
    tile[r][c] = src[(size_t)(s0 + r) * ND + d0 + c];
  }
  __syncthreads();
  us* oH = tHi + (size_t)b * ND * NS;
  us* oL = tLo + (size_t)b * ND * NS;
#pragma unroll
  for (int i = 0; i < 16; ++i) {
    int lin = (i << 8) + tid;
    int dr = lin >> 6, sc = lin & 63;
    float v = tile[sc][dr];
    size_t o = (size_t)(d0 + dr) * NS + s0 + sc;
    us h = f2bf(v);
    oH[o] = h;
    oL[o] = f2bf(v - bf2f(h));
  }
}

// ---------------- row softmax, in-place f32 + split planes ----------------
__global__ __launch_bounds__(256) void ga_softmax(float* __restrict__ al,
                                                  us* __restrict__ pHi, us* __restrict__ pLo) {
  int row = blockIdx.x;  // t*32 + b
  int tid = threadIdx.x;
  float* p = al + (size_t)row * NS;
  float4 v = *reinterpret_cast<const float4*>(p + (tid << 2));
  float m = fmaxf(fmaxf(v.x, v.y), fmaxf(v.z, v.w));
#pragma unroll
  for (int off = 32; off; off >>= 1) m = fmaxf(m, __shfl_xor(m, off));
  __shared__ float rmax[4], rsum[4];
  int wv = tid >> 6, ln = tid & 63;
  if (ln == 0) rmax[wv] = m;
  __syncthreads();
  m = fmaxf(fmaxf(rmax[0], rmax[1]), fmaxf(rmax[2], rmax[3]));
  float4 e;
  e.x = __expf(v.x - m); e.y = __expf(v.y - m);
  e.z = __expf(v.z - m); e.w = __expf(v.w - m);
  float s = e.x + e.y + e.z + e.w;
#pragma unroll
  for (int off = 32; off; off >>= 1) s += __shfl_xor(s, off);
  if (ln == 0) rsum[wv] = s;
  __syncthreads();
  s = rsum[0] + rsum[1] + rsum[2] + rsum[3];
  float inv = 1.0f / s;
  e.x *= inv; e.y *= inv; e.z *= inv; e.w *= inv;
  *reinterpret_cast<float4*>(p + (tid << 2)) = e;
  int t = row >> 5, b = row & 31;
  size_t o = ((size_t)b * NT_ + t) * NS + (tid << 2);
  ushort4 h, l;
  h.x = f2bf(e.x); l.x = f2bf(e.x - bf2f(h.x));
  h.y = f2bf(e.y); l.y = f2bf(e.y - bf2f(h.y));
  h.z = f2bf(e.z); l.z = f2bf(e.z - bf2f(h.z));
  h.w = f2bf(e.w); l.w = f2bf(e.w - bf2f(h.w));
  *reinterpret_cast<ushort4*>(pHi + o) = h;
  *reinterpret_cast<ushort4*>(pLo + o) = l;
}

// ---------------- split-bf16 GEMM (32x32x16): C[M,N] = A[M,K] * B[N,K]^T ----------------
__device__ inline void gload16(const us* g, void* l) {
  __builtin_amdgcn_global_load_lds((const __attribute__((address_space(1))) unsigned int*)g,
                                   (__attribute__((address_space(3))) unsigned int*)l, 16, 0, 0);
}

__device__ inline f32x16 mfma32(bf16x8 a, bf16x8 b, f32x16 c) {
  return __builtin_amdgcn_mfma_f32_32x32x16_bf16(a, b, c, 0, 0, 0);
}

// LDS per buffer: Ah[0,16K) Al[16K,32K) Bh[32K,48K) [Bl[48K,64K) if 3-term].
// Plane: 256 rows x 64B (32 bf16). Row r, physical 16B-block pb holds logical
// block pb ^ ((r>>1)&3)  (involution). Staging: thread tid writes phys
// (row=tid>>2 [+128], pb=tid&3) = linear tid*16 [+8192]; global source col =
// (pb ^ ((tid>>3)&3))*8 elems. Frag read (k-half H): lane: row=base+(lane&31),
// logical blk = 2H+(lane>>5), phys = logical ^ s, s=((lane&31)>>1)&3.
// -> every 32-lane frag read spreads over all 8 bank-quads (optimal 8cy/wave).
//
// Tile t (buf p=t&1), 2 k-half phases, 24 MFMA each (16 for 2-term):
//   ph0: read kh0 frags; stage ALL of tile t+1 -> buf p^1; bar; lgkm0; MFMA; bar
//   ph1: read kh1 frags; bar; lgkm0; MFMA; vmcnt(0) [loads ~2500cy old]; bar

#define STG_A(ST) do {                                                             \
    long kof_ = (long)(ST) << 5;                                                   \
    const us *ah_, *al_;                                                           \
    if constexpr (MODE == 3) {                                                     \
      if ((ST) < (NT >> 1)) { ah_ = pAh + kof_; al_ = pAl + kof_; }                \
      else { ah_ = pA2h + kof_ - 1024; al_ = pA2l + kof_ - 1024; }                 \
    } else { ah_ = pAh + kof_; al_ = pAl + kof_; }                                 \
    char* d_ = lb + (((ST) & 1) ? BUFSZ : 0) + (tid << 4);                         \
    gload16(ah_ + gA0, d_);                                                        \
    gload16(ah_ + gA1, d_ + 8192);                                                 \
    gload16(al_ + gA0, d_ + 16384);                                                \
    gload16(al_ + gA1, d_ + 24576);                                                \
  } while (0)

#define STG_B(ST) do {                                                             \
    long kof_ = (long)(ST) << 5;                                                   \
    char* d_ = lb + (((ST) & 1) ? BUFSZ : 0) + 32768 + (tid << 4);                 \
    gload16(pBh + gB0 + kof_, d_);                                                 \
    gload16(pBh + gB1 + kof_, d_ + 8192);                                          \
    if constexpr (SPLITB) {                                                        \
      gload16(pBl + gB0 + kof_, d_ + 16384);                                       \
      gload16(pBl + gB1 + kof_, d_ + 24576);                                       \
    }                                                                              \
  } while (0)

#define PHASE(H, STAGES, TAIL) do {                                                \
    const char* bp_ = lb + (cur ? BUFSZ : 0);                                      \
    const int xb_ = (H) ? xb1 : xb0;                                               \
    bf16x8 ah_[4], al_[4], bh_[2], bl_[2];                                         \
    _Pragma("unroll") for (int m = 0; m < 4; ++m) {                                \
      ah_[m] = *(const bf16x8*)(bp_ + aBase + (m << 11) + xb_);                    \
      al_[m] = *(const bf16x8*)(bp_ + 16384 + aBase + (m << 11) + xb_);            \
    }                                                                              \
    _Pragma("unroll") for (int n = 0; n < 2; ++n) {                                \
      bh_[n] = *(const bf16x8*)(bp_ + 32768 + bBase + (n << 11) + xb_);            \
      if constexpr (SPLITB)                                                        \
        bl_[n] = *(const bf16x8*)(bp_ + 49152 + bBase + (n << 11) + xb_);          \
    }                                                                              \
    STAGES;                                                                        \
    __builtin_amdgcn_s_barrier();                                                  \
    asm volatile("s_waitcnt lgkmcnt(0)" ::: "memory");                             \
    __builtin_amdgcn_sched_barrier(0);                                             \
    __builtin_amdgcn_s_setprio(1);                                                 \
    _Pragma("unroll") for (int m = 0; m < 4; ++m)                                  \
      _Pragma("unroll") for (int n = 0; n < 2; ++n)                                \
        acc[m][n] = mfma32(ah_[m], bh_[n], acc[m][n]);                             \
    if constexpr (SPLITB)                                                          \
      _Pragma("unroll") for (int m = 0; m < 4; ++m)                                \
        _Pragma("unroll") for (int n = 0; n < 2; ++n)                              \
          acc[m][n] = mfma32(ah_[m], bl_[n], acc[m][n]);                           \
    _Pragma("unroll") for (int m = 0; m < 4; ++m)                                  \
      _Pragma("unroll") for (int n = 0; n < 2; ++n)                                \
        acc[m][n] = mfma32(al_[m], bh_[n], acc[m][n]);                             \
    __builtin_amdgcn_s_setprio(0);                                                 \
    TAIL;                                                                          \
    __builtin_amdgcn_s_barrier();                                                  \
  } while (0)

// MODE 0: GEMM1 in*W_in^T -> h hi/lo planes.        grid(64,4,1)
// MODE 1: GEMM2 h*ctx^T   -> f32 align (t*32+b,s).  grid(2,4,32)
// MODE 2: GEMM3 P*ctxT^T  -> c hi/lo planes.        grid(2,4,32)
// MODE 3: GEMM4 concat[c,in]*W_out^T -> tanh f32.   grid(64,4,1), 2-term
template <int MODE>
__global__ __launch_bounds__(512, 2) void ga_gm32(
    const us* __restrict__ Ahi, const us* __restrict__ Alo,
    const us* __restrict__ A2hi, const us* __restrict__ A2lo,
    const us* __restrict__ Bhi, const us* __restrict__ Blo,
    void* __restrict__ out0, void* __restrict__ out1,
    int K, int lda, int ldb, long astride, long bstride) {
  constexpr bool SPLITB = (MODE != 3);
  constexpr int BUFSZ = SPLITB ? 65536 : 49152;
  __shared__ __align__(16) char lds[2 * BUFSZ];
  char* lb = lds;
  const int NT = K >> 5;
  const int tid = threadIdx.x;
  const int lane = tid & 63;
  const int l31 = lane & 31;
  const int hi5 = lane >> 5;
  const int wv = tid >> 6;
  const int wr = wv >> 2, wc = wv & 3;  // 2M x 4N waves, per-wave 128x64
  const int rowA = blockIdx.x << 8, colB = blockIdx.y << 8;
  const int bz = blockIdx.z;

  const us* pAh = Ahi + (size_t)bz * astride + (size_t)rowA * lda;
  const us* pAl = Alo + (size_t)bz * astride + (size_t)rowA * lda;
  const us* pA2h = (MODE == 3) ? A2hi + (size_t)rowA * lda : nullptr;
  const us* pA2l = (MODE == 3) ? A2lo + (size_t)rowA * lda : nullptr;
  const us* pBh = Bhi + (size_t)bz * bstride + (size_t)colB * ldb;
  const us* pBl = SPLITB ? Blo + (size_t)bz * bstride + (size_t)colB * ldb : nullptr;

  // staging source offsets (pre-swizzled global cols; linear LDS dest)
  const long swc = (long)(((tid & 3) ^ ((tid >> 3) & 3)) << 3);
  const long gA0 = (long)(tid >> 2) * lda + swc;
  const long gA1 = (long)((tid >> 2) + 128) * lda + swc;
  const long gB0 = (long)(tid >> 2) * ldb + swc;
  const long gB1 = (long)((tid >> 2) + 128) * ldb + swc;

  // frag read byte offsets (within plane), swizzled
  const int s_ = (l31 >> 1) & 3;
  const int xb0 = ((hi5 ^ s_) << 4);
  const int xb1 = (((2 | hi5) ^ s_) << 4);
  const int aBase = ((wr << 7) + l31) << 6;
  const int bBase = ((wc << 6) + l31) << 6;

  f32x16 acc[4][2];
#pragma unroll
  for (int m = 0; m < 4; ++m)
#pragma unroll
    for (int n = 0; n < 2; ++n)
#pragma unroll
      for (int g = 0; g < 16; ++g) acc[m][n][g] = 0.f;

  // prologue: tile0
  STG_A(0); STG_B(0);
  asm volatile("s_waitcnt vmcnt(0)" ::: "memory");
  __builtin_amdgcn_s_barrier();

  int cur = 0;
  for (int t = 0; t < NT; ++t) {
    const bool sg = (t + 1 < NT);
    PHASE(0, { if (sg) { STG_A(t + 1); STG_B(t + 1); } }, {});
    PHASE(1, {}, { asm volatile("s_waitcnt vmcnt(0)" ::: "memory"); });
    cur ^= 1;
  }

  // epilogue: C/D layout col=lane&31, row=(g&3)+8*(g>>2)+4*(lane>>5)
#pragma unroll
  for (int m = 0; m < 4; ++m)
#pragma unroll
    for (int n = 0; n < 2; ++n)
#pragma unroll
      for (int g = 0; g < 16; ++g) {
        int r = rowA + (wr << 7) + (m << 5) + (g & 3) + ((g >> 2) << 3) + (hi5 << 2);
        int c = colB + (wc << 6) + (n << 5) + l31;
        float v = acc[m][n][g];
        if constexpr (MODE == 0) {
          store_split((us*)out0, (us*)out1, (size_t)r * 1024 + c, v);
        } else if constexpr (MODE == 1) {
          ((float*)out0)[((size_t)r * NB + bz) * NS + c] = v;  // align[t][b][s]
        } else if constexpr (MODE == 2) {
          store_split((us*)out0, (us*)out1, ((size_t)bz * 512 + r) * 1024 + c, v);
        } else {
          int bb = r >> 9, tt2 = r & 511;
          ((float*)out0)[((size_t)tt2 * NB + bb) * ND + c] = tanhf(v);  // attn[t][b][d]
        }
      }
}

// ---------------- launch ----------------
extern "C" void kernel_launch(void* const* d_in, const int* in_sizes, int n_in,
                              void* d_out, int out_size, void* d_ws, size_t ws_size,
                              hipStream_t stream) {
  (void)in_sizes; (void)n_in; (void)out_size; (void)ws_size;
  const float* inp = (const float*)d_in[0];   // [32][512][1024]
  const float* ctx = (const float*)d_in[1];   // [32][1024][1024]
  const float* Win = (const float*)d_in[2];   // [1024][1024] (e,d)
  const float* Wout = (const float*)d_in[3];  // [1024][2048] (d,f)
  float* out = (float*)d_out;

  char* w = (char*)d_ws;
  us* ctx_hi  = (us*)(w + 0);
  us* c_hi    = (us*)(w + 0);
  us* c_lo    = (us*)(w + 33554432);
  us* ctx_lo  = (us*)(w + 67108864);
  us* p_hi    = (us*)(w + 67108864);
  us* p_lo    = (us*)(w + 100663296);
  us* in_hi   = (us*)(w + 134217728);
  us* in_lo   = (us*)(w + 167772160);
  us* h_hi    = (us*)(w + 201326592);
  us* h_lo    = (us*)(w + 234881024);
  us* ctxT_lo = (us*)(w + 201326592);  // reuses h region after GEMM2
  us* win_hi  = (us*)(w + 268435456);
  us* win_lo  = (us*)(w + 270532608);
  us* wout_b  = (us*)(w + 272629760);

  us* ctxT_hi = (us*)d_out;            // attn region as scratch until GEMM4
  float* alignOut = out + 16777216;    // second half of d_out

  ga_split<<<2048, 256, 0, stream>>>(inp, in_hi, in_lo, 16777216L);
  ga_split<<<2048, 256, 0, stream>>>(ctx, ctx_hi, ctx_lo, 33554432L);
  ga_split<<<512, 256, 0, stream>>>(Win, win_hi, win_lo, 1048576L);
  ga_cvt<<<512, 256, 0, stream>>>(Wout, wout_b, 2097152L);

  // GEMM1: h = in @ W_in^T   (M=16384, N=1024, K=1024)
  ga_gm32<0><<<dim3(64, 4, 1), 512, 0, stream>>>(in_hi, in_lo, nullptr, nullptr,
                                                 win_hi, win_lo, h_hi, h_lo,
                                                 1024, 1024, 1024, 0L, 0L);
  // GEMM2: align = h @ ctx^T (batched over 32; M=512, N=1024, K=1024)
  ga_gm32<1><<<dim3(2, 4, 32), 512, 0, stream>>>(h_hi, h_lo, nullptr, nullptr,
                                                 ctx_hi, ctx_lo, alignOut, nullptr,
                                                 1024, 1024, 1024, 524288L, 1048576L);
  // ctx transpose+split (overwrites h region -> must follow GEMM2; stream-ordered)
  ga_transpose_split<<<dim3(16, 16, 32), 256, 0, stream>>>(ctx, ctxT_hi, ctxT_lo);
  // softmax in-place + P split planes
  ga_softmax<<<16384, 256, 0, stream>>>(alignOut, p_hi, p_lo);
  // GEMM3: c = P @ ctx (via ctxT planes; batched; M=512, N=1024, K=1024)
  ga_gm32<2><<<dim3(2, 4, 32), 512, 0, stream>>>(p_hi, p_lo, nullptr, nullptr,
                                                 ctxT_hi, ctxT_lo, c_hi, c_lo,
                                                 1024, 1024, 1024, 524288L, 1048576L);
  // GEMM4: attn = tanh(concat[c,in] @ W_out^T) (M=16384, N=1024, K=2048, 2-term)
  ga_gm32<3><<<dim3(64, 4, 1), 512, 0, stream>>>(c_hi, c_lo, in_hi, in_lo,
                                                 wout_b, nullptr, out, nullptr,
                                                 2048, 1024, 2048, 0L, 0L);
}

// Round 6
// 619.889 us; speedup vs baseline: 1.1014x; 1.1014x over previous
//
#include <hip/hip_runtime.h>
#include <hip/hip_bf16.h>

// GlobalAttention (general): B=32, T=512, S=1024, D=1024, f32 in/out.
// Split-bf16 GEMMs expressed as K-SEGMENTED plain bf16 GEMMs:
//   3-term Markidis  A*B ~= Ah*Bh + Ah*Bl + Al*Bh  ==  [Ah|Ah|Al] x [Bh|Bl|Bh]
//   (one GEMM, K'=3K). GEMM4 (2-term per operand): K'=4096, 4 segments.
// GEMM engine = m201 8-phase 256x256 template:
//   BK=64, 8 waves (2Mx4N), per-wave 128x64, 16x16x32 MFMA, LDS 128KB
//   (2 buf x {A0,A1,B0,B1} 16KB halves), per phase: {ds_read quadrant ||
//   stage 1 half-tile (2 gload_lds)} -> barrier -> lgkm(0) -> 16 MFMA ->
//   barrier; vmcnt(4) ONLY at phases 4/8; setprio(1) around MFMA; read
//   swizzle byte^=((row&7)<<4) via pre-swizzled global source.
// Stage ledger (race-audited, round-5 fix): per iter i (X=2i):
//   p1:(X+1).A0  p2:(X+1).A1  p3:(X+2).B0  p4:(X+2).B1+vm4
//   p5:(X+2).A0  p6:(X+2).A1  p7:(X+3).B0  p8:(X+3).B1+vm4
// Region last-reads: buf.A=p3/p7, buf.B=p2/p6 -> every overwrite >=1 barrier
// after last read; vm4 leaves only the 2 newest half-tiles in flight.

typedef short bf16x8 __attribute__((ext_vector_type(8)));
typedef float f32x4 __attribute__((ext_vector_type(4)));
typedef unsigned short us;

#define NB 32
#define NT_ 512
#define NS 1024
#define ND 1024

__device__ inline us f2bf(float x) {
  unsigned u = __float_as_uint(x);
  u += 0x7FFFu + ((u >> 16) & 1u);
  return (us)(u >> 16);
}
__device__ inline float bf2f(us h) { return __uint_as_float(((unsigned)h) << 16); }

__device__ inline void store_split(us* __restrict__ hi, us* __restrict__ lo, size_t idx, float v) {
  us h = f2bf(v);
  hi[idx] = h;
  lo[idx] = f2bf(v - bf2f(h));
}

// ---------------- elementwise split / convert ----------------
__global__ void ga_split(const float* __restrict__ src, us* __restrict__ hi,
                         us* __restrict__ lo, long n) {
  long i0 = ((long)blockIdx.x * blockDim.x + threadIdx.x) * 4;
  long stride = (long)gridDim.x * blockDim.x * 4;
  for (long i = i0; i < n; i += stride) {
    float4 v = *reinterpret_cast<const float4*>(src + i);
    ushort4 h, l;
    h.x = f2bf(v.x); l.x = f2bf(v.x - bf2f(h.x));
    h.y = f2bf(v.y); l.y = f2bf(v.y - bf2f(h.y));
    h.z = f2bf(v.z); l.z = f2bf(v.z - bf2f(h.z));
    h.w = f2bf(v.w); l.w = f2bf(v.w - bf2f(h.w));
    *reinterpret_cast<ushort4*>(hi + i) = h;
    *reinterpret_cast<ushort4*>(lo + i) = l;
  }
}

__global__ void ga_cvt(const float* __restrict__ src, us* __restrict__ dst, long n) {
  long i0 = ((long)blockIdx.x * blockDim.x + threadIdx.x) * 4;
  long stride = (long)gridDim.x * blockDim.x * 4;
  for (long i = i0; i < n; i += stride) {
    float4 v = *reinterpret_cast<const float4*>(src + i);
    ushort4 h;
    h.x = f2bf(v.x); h.y = f2bf(v.y); h.z = f2bf(v.z); h.w = f2bf(v.w);
    *reinterpret_cast<ushort4*>(dst + i) = h;
  }
}

// ---------------- ctx transpose+split: [B][S][D] f32 -> [B][D][S] bf16 hi/lo ----------------
__global__ void ga_transpose_split(const float* __restrict__ ctx, us* __restrict__ tHi,
                                   us* __restrict__ tLo) {
  __shared__ float tile[64][65];
  int s0 = blockIdx.x << 6, d0 = blockIdx.y << 6, b = blockIdx.z;
  const float* src = ctx + (size_t)b * NS * ND;
  int tid = threadIdx.x;
#pragma unroll
  for (int i = 0; i < 16; ++i) {
    int lin = (i << 8) + tid;
    int r = lin >> 6, c = lin & 63;
    tile[r][c] = src[(size_t)(s0 + r) * ND + d0 + c];
  }
  __syncthreads();
  us* oH = tHi + (size_t)b * ND * NS;
  us* oL = tLo + (size_t)b * ND * NS;
#pragma unroll
  for (int i = 0; i < 16; ++i) {
    int lin = (i << 8) + tid;
    int dr = lin >> 6, sc = lin & 63;
    float v = tile[sc][dr];
    size_t o = (size_t)(d0 + dr) * NS + s0 + sc;
    us h = f2bf(v);
    oH[o] = h;
    oL[o] = f2bf(v - bf2f(h));
  }
}

// ---------------- row softmax, in-place f32 + split planes ----------------
__global__ __launch_bounds__(256) void ga_softmax(float* __restrict__ al,
                                                  us* __restrict__ pHi, us* __restrict__ pLo) {
  int row = blockIdx.x;  // t*32 + b
  int tid = threadIdx.x;
  float* p = al + (size_t)row * NS;
  float4 v = *reinterpret_cast<const float4*>(p + (tid << 2));
  float m = fmaxf(fmaxf(v.x, v.y), fmaxf(v.z, v.w));
#pragma unroll
  for (int off = 32; off; off >>= 1) m = fmaxf(m, __shfl_xor(m, off));
  __shared__ float rmax[4], rsum[4];
  int wv = tid >> 6, ln = tid & 63;
  if (ln == 0) rmax[wv] = m;
  __syncthreads();
  m = fmaxf(fmaxf(rmax[0], rmax[1]), fmaxf(rmax[2], rmax[3]));
  float4 e;
  e.x = __expf(v.x - m); e.y = __expf(v.y - m);
  e.z = __expf(v.z - m); e.w = __expf(v.w - m);
  float s = e.x + e.y + e.z + e.w;
#pragma unroll
  for (int off = 32; off; off >>= 1) s += __shfl_xor(s, off);
  if (ln == 0) rsum[wv] = s;
  __syncthreads();
  s = rsum[0] + rsum[1] + rsum[2] + rsum[3];
  float inv = 1.0f / s;
  e.x *= inv; e.y *= inv; e.z *= inv; e.w *= inv;
  *reinterpret_cast<float4*>(p + (tid << 2)) = e;
  int t = row >> 5, b = row & 31;
  size_t o = ((size_t)b * NT_ + t) * NS + (tid << 2);
  ushort4 h, l;
  h.x = f2bf(e.x); l.x = f2bf(e.x - bf2f(h.x));
  h.y = f2bf(e.y); l.y = f2bf(e.y - bf2f(h.y));
  h.z = f2bf(e.z); l.z = f2bf(e.z - bf2f(h.z));
  h.w = f2bf(e.w); l.w = f2bf(e.w - bf2f(h.w));
  *reinterpret_cast<ushort4*>(pHi + o) = h;
  *reinterpret_cast<ushort4*>(pLo + o) = l;
}

// ---------------- K-segmented bf16 GEMM, m201 8-phase engine ----------------
__device__ inline void gload16(const us* g, void* l) {
  __builtin_amdgcn_global_load_lds((const __attribute__((address_space(1))) unsigned int*)g,
                                   (__attribute__((address_space(3))) unsigned int*)l, 16, 0, 0);
}

__device__ inline f32x4 mfma16(bf16x8 a, bf16x8 b, f32x4 c) {
  return __builtin_amdgcn_mfma_f32_16x16x32_bf16(a, b, c, 0, 0, 0);
}

// LDS per buffer (64KB): A0[0,16K) A1[16K,32K) B0[32K,48K) B1[48K,64K).
// Half = 128 rows x 128B (BK=64). Phys 16B-block pb of row r holds logical
// block pb ^ (r&7); staging source col pre-swizzled, LDS dest linear.

#define VM4 asm volatile("s_waitcnt vmcnt(4)" ::: "memory")
#define VM0 asm volatile("s_waitcnt vmcnt(0)" ::: "memory")

#define STG_A(T, H) do {                                                           \
    int s3_ = (T) >> 4;                                                            \
    const us* ga_ = (MODE == 3)                                                    \
        ? ((s3_ == 0) ? pA0 : (s3_ == 1) ? pA1 : (s3_ == 2) ? pA2 : pA3)           \
        : ((s3_ == 2) ? pA1 : pA0);                                                \
    const us* g_ = ga_ + ((long)((T) & 15) << 6) + ((H) ? aOff1 : aOff0);          \
    char* d_ = lb + (((T) & 1) << 16) + ((H) << 14) + (tid << 4);                  \
    gload16(g_, d_);                                                               \
    gload16(g_ + ald64, d_ + 8192);                                                \
  } while (0)

#define STG_B(T, H) do {                                                           \
    int s3_ = (T) >> 4;                                                            \
    const us* gb_ = (MODE == 3) ? ((s3_ >= 2) ? pB2 : pB0)                         \
                                : ((s3_ == 1) ? pB1 : pB0);                        \
    const us* g_ = gb_ + ((long)((T) & 15) << 6) + ((H) ? bOff1 : bOff0);          \
    char* d_ = lb + (((T) & 1) << 16) + 32768 + ((H) << 14) + (tid << 4);          \
    gload16(g_, d_);                                                               \
    gload16(g_ + bld64, d_ + 8192);                                                \
  } while (0)

#define RD_A(BP, QM) do {                                                          \
    const char* p_ = (BP) + aRd + ((QM) << 13);                                    \
    _Pragma("unroll") for (int m_ = 0; m_ < 4; ++m_) {                             \
      a[m_][0] = *(const bf16x8*)(p_ + (m_ << 11) + colx0);                        \
      a[m_][1] = *(const bf16x8*)(p_ + (m_ << 11) + colx1);                        \
    }                                                                              \
  } while (0)

#define RD_B(BP, ARR, QN) do {                                                     \
    const char* p_ = (BP) + bRd + ((QN) << 12);                                    \
    _Pragma("unroll") for (int n_ = 0; n_ < 2; ++n_) {                             \
      ARR[n_][0] = *(const bf16x8*)(p_ + (n_ << 11) + colx0);                      \
      ARR[n_][1] = *(const bf16x8*)(p_ + (n_ << 11) + colx1);                      \
    }                                                                              \
  } while (0)

#define MM(QM, QN, ARR)                                                            \
  _Pragma("unroll") for (int ks_ = 0; ks_ < 2; ++ks_)                              \
  _Pragma("unroll") for (int m_ = 0; m_ < 4; ++m_)                                 \
  _Pragma("unroll") for (int n_ = 0; n_ < 2; ++n_)                                 \
    acc[(QM) * 4 + m_][(QN) * 2 + n_] =                                            \
        mfma16(a[m_][ks_], ARR[n_][ks_], acc[(QM) * 4 + m_][(QN) * 2 + n_])

#define PHX(RDS, STGS, TAILV, QM, QN, ARR) do {                                    \
    RDS;                                                                           \
    STGS;                                                                          \
    __builtin_amdgcn_s_barrier();                                                  \
    asm volatile("s_waitcnt lgkmcnt(0)" ::: "memory");                             \
    __builtin_amdgcn_sched_barrier(0);                                             \
    __builtin_amdgcn_s_setprio(1);                                                 \
    MM(QM, QN, ARR);                                                               \
    __builtin_amdgcn_s_setprio(0);                                                 \
    TAILV;                                                                         \
    __builtin_amdgcn_s_barrier();                                                  \
  } while (0)

// MODE 0: GEMM1 h=in*W_in^T, K'=3072 -> h planes.      grid(64,4,1)
// MODE 1: GEMM2 align=h*ctx^T, K'=3072 -> f32 align.   grid(2,4,32)
// MODE 2: GEMM3 c=P*ctxT^T, K'=3072 -> c planes.       grid(2,4,32)
// MODE 3: GEMM4 tanh(concat*W_out^T), K'=4096 -> out.  grid(64,4,1)
template <int MODE>
__global__ __launch_bounds__(512, 2) void ga_g8(
    const us* __restrict__ Ahi, const us* __restrict__ Alo,
    const us* __restrict__ A2hi, const us* __restrict__ A2lo,
    const us* __restrict__ Bhi, const us* __restrict__ Blo,
    void* __restrict__ out0, void* __restrict__ out1,
    int K, int lda, int ldb, long astride, long bstride) {
  __shared__ __align__(16) char lds[131072];
  char* lb = lds;
  const int NTILES = K >> 6;
  const int NIT = NTILES >> 1;
  const int tid = threadIdx.x;
  const int lane = tid & 63;
  const int fr = lane & 15;
  const int wv = tid >> 6;
  const int wr = wv >> 2, wc = wv & 3;  // 2M x 4N waves, per-wave 128x64
  const int rowA = blockIdx.x << 8, colB = blockIdx.y << 8;
  const int bz = blockIdx.z;

  // segment base pointers (block-adjusted)
  const us* pA0 = Ahi + (size_t)bz * astride + (size_t)rowA * lda;
  const us* pA1 = Alo + (size_t)bz * astride + (size_t)rowA * lda;
  const us* pA2 = (MODE == 3) ? A2hi + (size_t)rowA * lda : nullptr;
  const us* pA3 = (MODE == 3) ? A2lo + (size_t)rowA * lda : nullptr;
  const us* pB0 = Bhi + (size_t)bz * bstride + (size_t)colB * ldb;
  const us* pB1 = (MODE == 3) ? nullptr : Blo + (size_t)bz * bstride + (size_t)colB * ldb;
  const us* pB2 = (MODE == 3) ? pB0 + 1024 : nullptr;

  // staging geometry (pre-swizzled global source, linear LDS dest)
  const int arow = tid >> 3;
  const long swe = (long)(((tid & 7) ^ (arow & 7)) << 3);
  const long aOff0 = (long)arow * lda + swe;
  const long aOff1 = aOff0 + 128L * lda;
  const long ald64 = 64L * lda;
  const long bOff0 = (long)arow * ldb + swe;
  const long bOff1 = bOff0 + 128L * ldb;
  const long bld64 = 64L * ldb;

  // frag-read geometry (swizzled)
  const int l16 = ((lane >> 4) & 3) << 4;
  const int colx0 = l16 ^ ((fr & 7) << 4);
  const int colx1 = colx0 ^ 64;
  const int aRd = (wr << 14) + (fr << 7);
  const int bRd = 32768 + ((wc >> 1) << 14) + ((wc & 1) << 13) + (fr << 7);
  const char* B0P = lb;
  const char* B1P = lb + 65536;

  bf16x8 a[4][2], b0[2][2], b1[2][2];
  f32x4 zero = {0.f, 0.f, 0.f, 0.f};
  f32x4 acc[8][4];
#pragma unroll
  for (int i = 0; i < 8; ++i)
#pragma unroll
    for (int k = 0; k < 4; ++k) acc[i][k] = zero;

  // prologue: tile0 full + tile1.{B0,B1}; vm4 -> tile0 landed
  STG_A(0, 0); STG_A(0, 1); STG_B(0, 0); STG_B(0, 1);
  STG_B(1, 0); STG_B(1, 1);
  VM4;
  __builtin_amdgcn_s_barrier();

  for (int i = 0; i < NIT - 1; ++i) {
    const int X = i << 1;
    PHX({ RD_A(B0P, 0); RD_B(B0P, b0, 0); }, STG_A(X + 1, 0), , 0, 0, b0);
    PHX(RD_B(B0P, b1, 1),                    STG_A(X + 1, 1), , 0, 1, b1);
    PHX(RD_A(B0P, 1),                        STG_B(X + 2, 0), , 1, 1, b1);
    PHX(,                                    STG_B(X + 2, 1), VM4, 1, 0, b0);
    PHX({ RD_A(B1P, 0); RD_B(B1P, b0, 0); }, STG_A(X + 2, 0), , 0, 0, b0);
    PHX(RD_B(B1P, b1, 1),                    STG_A(X + 2, 1), , 0, 1, b1);
    PHX(RD_A(B1P, 1),                        STG_B(X + 3, 0), , 1, 1, b1);
    PHX(,                                    STG_B(X + 3, 1), VM4, 1, 0, b0);
  }
  {  // peeled last pair (X = NTILES-2): stage only (X+1).A; drain at p4
    const int X = NTILES - 2;
    PHX({ RD_A(B0P, 0); RD_B(B0P, b0, 0); }, STG_A(X + 1, 0), , 0, 0, b0);
    PHX(RD_B(B0P, b1, 1),                    STG_A(X + 1, 1), , 0, 1, b1);
    PHX(RD_A(B0P, 1), , , 1, 1, b1);
    PHX(, , VM0, 1, 0, b0);
    PHX({ RD_A(B1P, 0); RD_B(B1P, b0, 0); }, , , 0, 0, b0);
    PHX(RD_B(B1P, b1, 1), , , 0, 1, b1);
    PHX(RD_A(B1P, 1), , , 1, 1, b1);
    PHX(, , , 1, 0, b0);
  }

  // epilogue: C/D layout col=lane&15, row=(lane>>4)*4+j
#pragma unroll
  for (int mf = 0; mf < 8; ++mf)
#pragma unroll
    for (int nf = 0; nf < 4; ++nf)
#pragma unroll
      for (int j = 0; j < 4; ++j) {
        int r = rowA + (wr << 7) + (mf << 4) + (((lane >> 4) & 3) << 2) + j;
        int c = colB + (wc << 6) + (nf << 4) + fr;
        float v = acc[mf][nf][j];
        if constexpr (MODE == 0) {
          store_split((us*)out0, (us*)out1, (size_t)r * 1024 + c, v);
        } else if constexpr (MODE == 1) {
          ((float*)out0)[((size_t)r * NB + bz) * NS + c] = v;  // align[t][b][s]
        } else if constexpr (MODE == 2) {
          store_split((us*)out0, (us*)out1, ((size_t)bz * 512 + r) * 1024 + c, v);
        } else {
          int bb = r >> 9, tt2 = r & 511;
          ((float*)out0)[((size_t)tt2 * NB + bb) * ND + c] = tanhf(v);  // attn[t][b][d]
        }
      }
}

// ---------------- launch ----------------
extern "C" void kernel_launch(void* const* d_in, const int* in_sizes, int n_in,
                              void* d_out, int out_size, void* d_ws, size_t ws_size,
                              hipStream_t stream) {
  (void)in_sizes; (void)n_in; (void)out_size; (void)ws_size;
  const float* inp = (const float*)d_in[0];   // [32][512][1024]
  const float* ctx = (const float*)d_in[1];   // [32][1024][1024]
  const float* Win = (const float*)d_in[2];   // [1024][1024] (e,d)
  const float* Wout = (const float*)d_in[3];  // [1024][2048] (d,f)
  float* out = (float*)d_out;

  char* w = (char*)d_ws;
  us* ctx_hi  = (us*)(w + 0);
  us* c_hi    = (us*)(w + 0);
  us* c_lo    = (us*)(w + 33554432);
  us* ctx_lo  = (us*)(w + 67108864);
  us* p_hi    = (us*)(w + 67108864);
  us* p_lo    = (us*)(w + 100663296);
  us* in_hi   = (us*)(w + 134217728);
  us* in_lo   = (us*)(w + 167772160);
  us* h_hi    = (us*)(w + 201326592);
  us* h_lo    = (us*)(w + 234881024);
  us* ctxT_lo = (us*)(w + 201326592);  // reuses h region after GEMM2
  us* win_hi  = (us*)(w + 268435456);
  us* win_lo  = (us*)(w + 270532608);
  us* wout_b  = (us*)(w + 272629760);

  us* ctxT_hi = (us*)d_out;            // attn region as scratch until GEMM4
  float* alignOut = out + 16777216;    // second half of d_out

  ga_split<<<2048, 256, 0, stream>>>(inp, in_hi, in_lo, 16777216L);
  ga_split<<<2048, 256, 0, stream>>>(ctx, ctx_hi, ctx_lo, 33554432L);
  ga_split<<<512, 256, 0, stream>>>(Win, win_hi, win_lo, 1048576L);
  ga_cvt<<<512, 256, 0, stream>>>(Wout, wout_b, 2097152L);

  // GEMM1: h = in @ W_in^T   (M=16384, N=1024, K'=3072)
  ga_g8<0><<<dim3(64, 4, 1), 512, 0, stream>>>(in_hi, in_lo, nullptr, nullptr,
                                               win_hi, win_lo, h_hi, h_lo,
                                               3072, 1024, 1024, 0L, 0L);
  // GEMM2: align = h @ ctx^T (batched 32; M=512, N=1024, K'=3072)
  ga_g8<1><<<dim3(2, 4, 32), 512, 0, stream>>>(h_hi, h_lo, nullptr, nullptr,
                                               ctx_hi, ctx_lo, alignOut, nullptr,
                                               3072, 1024, 1024, 524288L, 1048576L);
  // ctx transpose+split (overwrites h region -> must follow GEMM2; stream-ordered)
  ga_transpose_split<<<dim3(16, 16, 32), 256, 0, stream>>>(ctx, ctxT_hi, ctxT_lo);
  // softmax in-place + P split planes
  ga_softmax<<<16384, 256, 0, stream>>>(alignOut, p_hi, p_lo);
  // GEMM3: c = P @ ctx (via ctxT planes; batched; M=512, N=1024, K'=3072)
  ga_g8<2><<<dim3(2, 4, 32), 512, 0, stream>>>(p_hi, p_lo, nullptr, nullptr,
                                               ctxT_hi, ctxT_lo, c_hi, c_lo,
                                               3072, 1024, 1024, 524288L, 1048576L);
  // GEMM4: attn = tanh(concat[c,in] @ W_out^T) (M=16384, N=1024, K'=4096)
  ga_g8<3><<<dim3(64, 4, 1), 512, 0, stream>>>(c_hi, c_lo, in_hi, in_lo,
                                               wout_b, nullptr, out, nullptr,
                                               4096, 1024, 2048, 0L, 0L);
}

// Round 9
// 613.414 us; speedup vs baseline: 1.1130x; 1.0106x over previous
//
#include <hip/hip_runtime.h>
#include <hip/hip_bf16.h>

// GlobalAttention (general): B=32, T=512, S=1024, D=1024, f32 in/out.
// Split-bf16 GEMMs as K-SEGMENTED plain bf16 GEMMs (Markidis 3-term =
// [Ah|Ah|Al]x[Bh|Bl|Bh], K'=3072; GEMM4 4-seg K'=4096).
// Engine: 256x256 tile, BK=64, 8 waves (2Mx4N), 16x16x32 MFMA, LDS 128KB
// (2 buf x {A0,A1,B0,B1} 16KB halves), 1 barrier/phase, 8 phases / 2 tiles.
// A frags read IN-PHASE pre-MM (compiler counted-lgkm per use); B frags read
// ONE PHASE AHEAD (post-MM p4/p8). No manual lgkm/sched_barrier.
// ROUND-9 FIX (WAR race): stage slots shifted +1 phase so every LDS overwrite
// issues >=1 barrier AFTER its region's reads drained (drain = consuming
// MFMA's register wait; wave can't pass the next barrier without it):
//   p1:A1(X+1) p2:B0(X+2) p3:B1(X+2) p4:A0(X+2)
//   p5:A1(X+2) p6:B0(X+3) p7:B1(X+3) p8:A0(X+3)
// WAR audit: B0 pre-read drains p1/p5-MM, overwrite p2/p6 (1 bar); B1 drains
// p2/p6-MM, overwrite p3/p7 (1 bar); A0 drains p1/p5-MM, overwrite p4/p8;
// A1 drains p3/p7-MM, overwrite p5/next-p1. Land audit (VM4 each phase =
// stage@pk confirmed by p(k+2), +1 bar before first read): tightest
// A0(X+3)@p8 -> confirmed next-p2, read next-p5. Peel: stage A1(NT-1)@p1,
// VM0@p3-post publishes via barrier_p4 before p4 pre-reads / p5,p7 reads.

typedef short bf16x8 __attribute__((ext_vector_type(8)));
typedef float f32x4 __attribute__((ext_vector_type(4)));
typedef unsigned short us;

#define NB 32
#define NT_ 512
#define NS 1024
#define ND 1024

__device__ inline us f2bf(float x) {
  unsigned u = __float_as_uint(x);
  u += 0x7FFFu + ((u >> 16) & 1u);
  return (us)(u >> 16);
}
__device__ inline float bf2f(us h) { return __uint_as_float(((unsigned)h) << 16); }

__device__ inline void store_split(us* __restrict__ hi, us* __restrict__ lo, size_t idx, float v) {
  us h = f2bf(v);
  hi[idx] = h;
  lo[idx] = f2bf(v - bf2f(h));
}

// ---------------- elementwise split / convert ----------------
__global__ void ga_split(const float* __restrict__ src, us* __restrict__ hi,
                         us* __restrict__ lo, long n) {
  long i0 = ((long)blockIdx.x * blockDim.x + threadIdx.x) * 4;
  long stride = (long)gridDim.x * blockDim.x * 4;
  for (long i = i0; i < n; i += stride) {
    float4 v = *reinterpret_cast<const float4*>(src + i);
    ushort4 h, l;
    h.x = f2bf(v.x); l.x = f2bf(v.x - bf2f(h.x));
    h.y = f2bf(v.y); l.y = f2bf(v.y - bf2f(h.y));
    h.z = f2bf(v.z); l.z = f2bf(v.z - bf2f(h.z));
    h.w = f2bf(v.w); l.w = f2bf(v.w - bf2f(h.w));
    *reinterpret_cast<ushort4*>(hi + i) = h;
    *reinterpret_cast<ushort4*>(lo + i) = l;
  }
}

__global__ void ga_cvt(const float* __restrict__ src, us* __restrict__ dst, long n) {
  long i0 = ((long)blockIdx.x * blockDim.x + threadIdx.x) * 4;
  long stride = (long)gridDim.x * blockDim.x * 4;
  for (long i = i0; i < n; i += stride) {
    float4 v = *reinterpret_cast<const float4*>(src + i);
    ushort4 h;
    h.x = f2bf(v.x); h.y = f2bf(v.y); h.z = f2bf(v.z); h.w = f2bf(v.w);
    *reinterpret_cast<ushort4*>(dst + i) = h;
  }
}

// ---------------- ctx transpose+split: [B][S][D] f32 -> [B][D][S] bf16 hi/lo ----------------
__global__ void ga_transpose_split(const float* __restrict__ ctx, us* __restrict__ tHi,
                                   us* __restrict__ tLo) {
  __shared__ float tile[64][65];
  int s0 = blockIdx.x << 6, d0 = blockIdx.y << 6, b = blockIdx.z;
  const float* src = ctx + (size_t)b * NS * ND;
  int tid = threadIdx.x;
#pragma unroll
  for (int i = 0; i < 16; ++i) {
    int lin = (i << 8) + tid;
    int r = lin >> 6, c = lin & 63;
    tile[r][c] = src[(size_t)(s0 + r) * ND + d0 + c];
  }
  __syncthreads();
  us* oH = tHi + (size_t)b * ND * NS;
  us* oL = tLo + (size_t)b * ND * NS;
#pragma unroll
  for (int i = 0; i < 16; ++i) {
    int lin = (i << 8) + tid;
    int dr = lin >> 6, sc = lin & 63;
    float v = tile[sc][dr];
    size_t o = (size_t)(d0 + dr) * NS + s0 + sc;
    us h = f2bf(v);
    oH[o] = h;
    oL[o] = f2bf(v - bf2f(h));
  }
}

// ---------------- row softmax, in-place f32 + split planes ----------------
__global__ __launch_bounds__(256) void ga_softmax(float* __restrict__ al,
                                                  us* __restrict__ pHi, us* __restrict__ pLo) {
  int row = blockIdx.x;  // t*32 + b
  int tid = threadIdx.x;
  float* p = al + (size_t)row * NS;
  float4 v = *reinterpret_cast<const float4*>(p + (tid << 2));
  float m = fmaxf(fmaxf(v.x, v.y), fmaxf(v.z, v.w));
#pragma unroll
  for (int off = 32; off; off >>= 1) m = fmaxf(m, __shfl_xor(m, off));
  __shared__ float rmax[4], rsum[4];
  int wv = tid >> 6, ln = tid & 63;
  if (ln == 0) rmax[wv] = m;
  __syncthreads();
  m = fmaxf(fmaxf(rmax[0], rmax[1]), fmaxf(rmax[2], rmax[3]));
  float4 e;
  e.x = __expf(v.x - m); e.y = __expf(v.y - m);
  e.z = __expf(v.z - m); e.w = __expf(v.w - m);
  float s = e.x + e.y + e.z + e.w;
#pragma unroll
  for (int off = 32; off; off >>= 1) s += __shfl_xor(s, off);
  if (ln == 0) rsum[wv] = s;
  __syncthreads();
  s = rsum[0] + rsum[1] + rsum[2] + rsum[3];
  float inv = 1.0f / s;
  e.x *= inv; e.y *= inv; e.z *= inv; e.w *= inv;
  *reinterpret_cast<float4*>(p + (tid << 2)) = e;
  int t = row >> 5, b = row & 31;
  size_t o = ((size_t)b * NT_ + t) * NS + (tid << 2);
  ushort4 h, l;
  h.x = f2bf(e.x); l.x = f2bf(e.x - bf2f(h.x));
  h.y = f2bf(e.y); l.y = f2bf(e.y - bf2f(h.y));
  h.z = f2bf(e.z); l.z = f2bf(e.z - bf2f(h.z));
  h.w = f2bf(e.w); l.w = f2bf(e.w - bf2f(h.w));
  *reinterpret_cast<ushort4*>(pHi + o) = h;
  *reinterpret_cast<ushort4*>(pLo + o) = l;
}

// ---------------- K-segmented bf16 GEMM, compiler-waited overlap engine ----------------
__device__ inline void gload16(const us* g, void* l) {
  __builtin_amdgcn_global_load_lds((const __attribute__((address_space(1))) unsigned int*)g,
                                   (__attribute__((address_space(3))) unsigned int*)l, 16, 0, 0);
}

__device__ inline f32x4 mfma16(bf16x8 a, bf16x8 b, f32x4 c) {
  return __builtin_amdgcn_mfma_f32_16x16x32_bf16(a, b, c, 0, 0, 0);
}

#define VM4 asm volatile("s_waitcnt vmcnt(4)" ::: "memory")
#define VM0 asm volatile("s_waitcnt vmcnt(0)" ::: "memory")

#define STG_A(T, H) do {                                                           \
    int s3_ = (T) >> 4;                                                            \
    const us* ga_ = (MODE == 3)                                                    \
        ? ((s3_ == 0) ? pA0 : (s3_ == 1) ? pA1 : (s3_ == 2) ? pA2 : pA3)           \
        : ((s3_ == 2) ? pA1 : pA0);                                                \
    const us* g_ = ga_ + (((T) & 15) << 6) + ((H) ? 131072 : 0) + aOff0;           \
    char* d_ = lb + (((T) & 1) << 16) + ((H) << 14) + (tid << 4);                  \
    gload16(g_, d_);                                                               \
    gload16(g_ + 65536, d_ + 8192);                                                \
  } while (0)

#define STG_B(T, H) do {                                                           \
    int s3_ = (T) >> 4;                                                            \
    const us* gb_ = (MODE == 3) ? ((s3_ >= 2) ? pB2 : pB0)                         \
                                : ((s3_ == 1) ? pB1 : pB0);                        \
    const us* g_ = gb_ + (((T) & 15) << 6) + ((H) ? (LDB << 7) : 0) + bOff0;       \
    char* d_ = lb + (((T) & 1) << 16) + 32768 + ((H) << 14) + (tid << 4);          \
    gload16(g_, d_);                                                               \
    gload16(g_ + (LDB << 6), d_ + 8192);                                           \
  } while (0)

#define RD_A(BP, ARR, QM) do {                                                     \
    const char* p_ = (BP) + aRd + ((QM) << 13);                                    \
    _Pragma("unroll") for (int m_ = 0; m_ < 4; ++m_) {                             \
      ARR[m_][0] = *(const bf16x8*)(p_ + (m_ << 11) + colx0);                      \
      ARR[m_][1] = *(const bf16x8*)(p_ + (m_ << 11) + colx1);                      \
    }                                                                              \
  } while (0)

#define RD_B(BP, ARR, QN) do {                                                     \
    const char* p_ = (BP) + bRd + ((QN) << 12);                                    \
    _Pragma("unroll") for (int n_ = 0; n_ < 2; ++n_) {                             \
      ARR[n_][0] = *(const bf16x8*)(p_ + (n_ << 11) + colx0);                      \
      ARR[n_][1] = *(const bf16x8*)(p_ + (n_ << 11) + colx1);                      \
    }                                                                              \
  } while (0)

// m-outer so the first MFMA unlocks after A[0]'s 2 reads (B pre-read earlier)
#define MM(QM, QN, AA, BB)                                                         \
  _Pragma("unroll") for (int m_ = 0; m_ < 4; ++m_)                                 \
  _Pragma("unroll") for (int ks_ = 0; ks_ < 2; ++ks_)                              \
  _Pragma("unroll") for (int n_ = 0; n_ < 2; ++n_)                                 \
    acc[(QM) * 4 + m_][(QN) * 2 + n_] =                                            \
        mfma16(AA[m_][ks_], BB[n_][ks_], acc[(QM) * 4 + m_][(QN) * 2 + n_])

#define PH(RDS, MMQ, POST) do {                                                    \
    __builtin_amdgcn_s_barrier();                                                  \
    RDS;                                                                           \
    __builtin_amdgcn_s_setprio(1);                                                 \
    MMQ;                                                                           \
    __builtin_amdgcn_s_setprio(0);                                                 \
    POST;                                                                          \
  } while (0)

// MODE 0: GEMM1 h=in*W_in^T, K'=3072 -> h planes.      grid(64,4,1)
// MODE 1: GEMM2 align=h*ctx^T, K'=3072 -> f32 align.   grid(2,4,32)
// MODE 2: GEMM3 c=P*ctxT^T, K'=3072 -> c planes.       grid(2,4,32)
// MODE 3: GEMM4 tanh(concat*W_out^T), K'=4096 -> out.  grid(64,4,1)
template <int MODE>
__global__ __launch_bounds__(512, 1) void ga_gb(
    const us* __restrict__ Ahi, const us* __restrict__ Alo,
    const us* __restrict__ A2hi, const us* __restrict__ A2lo,
    const us* __restrict__ Bhi, const us* __restrict__ Blo,
    void* __restrict__ out0, void* __restrict__ out1,
    long astride, long bstride) {
  constexpr int LDB = (MODE == 3) ? 2048 : 1024;
  constexpr int NT = (MODE == 3) ? 64 : 48;
  constexpr int NIT = NT >> 1;
  __shared__ __align__(16) char lds[131072];
  char* lb = lds;
  const int tid = threadIdx.x;
  const int lane = tid & 63;
  const int fr = lane & 15;
  const int wv = tid >> 6;
  const int wr = wv >> 2, wc = wv & 3;  // 2M x 4N waves, per-wave 128x64
  const int rowA = blockIdx.x << 8, colB = blockIdx.y << 8;
  const int bz = blockIdx.z;

  // segment base pointers (uniform -> SGPR)
  const us* pA0 = Ahi + (size_t)bz * astride + (size_t)rowA * 1024;
  const us* pA1 = Alo + (size_t)bz * astride + (size_t)rowA * 1024;
  const us* pA2 = (MODE == 3) ? A2hi + (size_t)rowA * 1024 : nullptr;
  const us* pA3 = (MODE == 3) ? A2lo + (size_t)rowA * 1024 : nullptr;
  const us* pB0 = Bhi + (size_t)bz * bstride + (size_t)colB * LDB;
  const us* pB1 = (MODE == 3) ? nullptr : Blo + (size_t)bz * bstride + (size_t)colB * LDB;
  const us* pB2 = (MODE == 3) ? pB0 + 1024 : nullptr;

  // staging geometry (pre-swizzled global source col, linear LDS dest)
  const int arow = tid >> 3;
  const int swe = ((tid & 7) ^ (arow & 7)) << 3;
  const int aOff0 = arow * 1024 + swe;
  const int bOff0 = arow * LDB + swe;

  // frag-read geometry (swizzled)
  const int l16 = ((lane >> 4) & 3) << 4;
  const int colx0 = l16 ^ ((fr & 7) << 4);
  const int colx1 = colx0 ^ 64;
  const int aRd = (wr << 14) + (fr << 7);
  const int bRd = 32768 + ((wc >> 1) << 14) + ((wc & 1) << 13) + (fr << 7);
  const char* BUF0 = lb;
  const char* BUF1 = lb + 65536;

  bf16x8 a4[4][2], b0[2][2], b1[2][2];
  f32x4 zero = {0.f, 0.f, 0.f, 0.f};
  f32x4 acc[8][4];
#pragma unroll
  for (int i = 0; i < 8; ++i)
#pragma unroll
    for (int k = 0; k < 4; ++k) acc[i][k] = zero;

  // prologue: stage tile0 full + tile1.{B0,B1,A0} (14 loads); drain all;
  // barrier publishes; pre-read tile0's B fragments.
  STG_B(0, 0); STG_B(0, 1); STG_A(0, 0); STG_A(0, 1);
  STG_B(1, 0); STG_B(1, 1); STG_A(1, 0);
  VM0;
  __builtin_amdgcn_s_barrier();
  RD_B(BUF0, b0, 0); RD_B(BUF0, b1, 1);

  for (int i = 0; i < NIT - 1; ++i) {
    const int X = i << 1;
    PH(RD_A(BUF0, a4, 0), MM(0, 0, a4, b0), { STG_A(X + 1, 1); VM4; });
    PH(,                  MM(0, 1, a4, b1), { STG_B(X + 2, 0); VM4; });
    PH(RD_A(BUF0, a4, 1), MM(1, 0, a4, b0), { STG_B(X + 2, 1); VM4; });
    PH(,                  MM(1, 1, a4, b1),
       { RD_B(BUF1, b0, 0); RD_B(BUF1, b1, 1); STG_A(X + 2, 0); VM4; });
    PH(RD_A(BUF1, a4, 0), MM(0, 0, a4, b0), { STG_A(X + 2, 1); VM4; });
    PH(,                  MM(0, 1, a4, b1), { STG_B(X + 3, 0); VM4; });
    PH(RD_A(BUF1, a4, 1), MM(1, 0, a4, b0), { STG_B(X + 3, 1); VM4; });
    PH(,                  MM(1, 1, a4, b1),
       { RD_B(BUF0, b0, 0); RD_B(BUF0, b1, 1); STG_A(X + 3, 0); VM4; });
  }
  // peeled last pair (tiles NT-2 in BUF0, NT-1 in BUF1): stage only
  // A1(NT-1)@p1; VM0@p3-post drains it, barrier_p4 publishes before the
  // p4 pre-reads and the p5/p7 A reads of BUF1.
  PH(RD_A(BUF0, a4, 0), MM(0, 0, a4, b0), { STG_A(NT - 1, 1); VM4; });
  PH(,                  MM(0, 1, a4, b1), {});
  PH(RD_A(BUF0, a4, 1), MM(1, 0, a4, b0), { VM0; });
  PH(,                  MM(1, 1, a4, b1),
     { RD_B(BUF1, b0, 0); RD_B(BUF1, b1, 1); });
  PH(RD_A(BUF1, a4, 0), MM(0, 0, a4, b0), {});
  PH(,                  MM(0, 1, a4, b1), {});
  PH(RD_A(BUF1, a4, 1), MM(1, 0, a4, b0), {});
  PH(,                  MM(1, 1, a4, b1), {});

  // epilogue: C/D layout col=lane&15, row=(lane>>4)*4+j
#pragma unroll
  for (int mf = 0; mf < 8; ++mf)
#pragma unroll
    for (int nf = 0; nf < 4; ++nf)
#pragma unroll
      for (int j = 0; j < 4; ++j) {
        int r = rowA + (wr << 7) + (mf << 4) + (((lane >> 4) & 3) << 2) + j;
        int c = colB + (wc << 6) + (nf << 4) + fr;
        float v = acc[mf][nf][j];
        if constexpr (MODE == 0) {
          store_split((us*)out0, (us*)out1, (size_t)r * 1024 + c, v);
        } else if constexpr (MODE == 1) {
          ((float*)out0)[((size_t)r * NB + bz) * NS + c] = v;  // align[t][b][s]
        } else if constexpr (MODE == 2) {
          store_split((us*)out0, (us*)out1, ((size_t)bz * 512 + r) * 1024 + c, v);
        } else {
          int bb = r >> 9, tt2 = r & 511;
          ((float*)out0)[((size_t)tt2 * NB + bb) * ND + c] = tanhf(v);  // attn[t][b][d]
        }
      }
}

// ---------------- launch ----------------
extern "C" void kernel_launch(void* const* d_in, const int* in_sizes, int n_in,
                              void* d_out, int out_size, void* d_ws, size_t ws_size,
                              hipStream_t stream) {
  (void)in_sizes; (void)n_in; (void)out_size; (void)ws_size;
  const float* inp = (const float*)d_in[0];   // [32][512][1024]
  const float* ctx = (const float*)d_in[1];   // [32][1024][1024]
  const float* Win = (const float*)d_in[2];   // [1024][1024] (e,d)
  const float* Wout = (const float*)d_in[3];  // [1024][2048] (d,f)
  float* out = (float*)d_out;

  char* w = (char*)d_ws;
  us* ctx_hi  = (us*)(w + 0);
  us* c_hi    = (us*)(w + 0);
  us* c_lo    = (us*)(w + 33554432);
  us* ctx_lo  = (us*)(w + 67108864);
  us* p_hi    = (us*)(w + 67108864);
  us* p_lo    = (us*)(w + 100663296);
  us* in_hi   = (us*)(w + 134217728);
  us* in_lo   = (us*)(w + 167772160);
  us* h_hi    = (us*)(w + 201326592);
  us* h_lo    = (us*)(w + 234881024);
  us* ctxT_lo = (us*)(w + 201326592);  // reuses h region after GEMM2
  us* win_hi  = (us*)(w + 268435456);
  us* win_lo  = (us*)(w + 270532608);
  us* wout_b  = (us*)(w + 272629760);

  us* ctxT_hi = (us*)d_out;            // attn region as scratch until GEMM4
  float* alignOut = out + 16777216;    // second half of d_out

  ga_split<<<2048, 256, 0, stream>>>(inp, in_hi, in_lo, 16777216L);
  ga_split<<<2048, 256, 0, stream>>>(ctx, ctx_hi, ctx_lo, 33554432L);
  ga_split<<<512, 256, 0, stream>>>(Win, win_hi, win_lo, 1048576L);
  ga_cvt<<<512, 256, 0, stream>>>(Wout, wout_b, 2097152L);

  // GEMM1: h = in @ W_in^T   (M=16384, N=1024, K'=3072)
  ga_gb<0><<<dim3(64, 4, 1), 512, 0, stream>>>(in_hi, in_lo, nullptr, nullptr,
                                               win_hi, win_lo, h_hi, h_lo, 0L, 0L);
  // GEMM2: align = h @ ctx^T (batched 32; M=512, N=1024, K'=3072)
  ga_gb<1><<<dim3(2, 4, 32), 512, 0, stream>>>(h_hi, h_lo, nullptr, nullptr,
                                               ctx_hi, ctx_lo, alignOut, nullptr,
                                               524288L, 1048576L);
  // ctx transpose+split (overwrites h region -> must follow GEMM2; stream-ordered)
  ga_transpose_split<<<dim3(16, 16, 32), 256, 0, stream>>>(ctx, ctxT_hi, ctxT_lo);
  // softmax in-place + P split planes
  ga_softmax<<<16384, 256, 0, stream>>>(alignOut, p_hi, p_lo);
  // GEMM3: c = P @ ctx (via ctxT planes; batched; M=512, N=1024, K'=3072)
  ga_gb<2><<<dim3(2, 4, 32), 512, 0, stream>>>(p_hi, p_lo, nullptr, nullptr,
                                               ctxT_hi, ctxT_lo, c_hi, c_lo,
                                               524288L, 1048576L);
  // GEMM4: attn = tanh(concat[c,in] @ W_out^T) (M=16384, N=1024, K'=4096)
  ga_gb<3><<<dim3(64, 4, 1), 512, 0, stream>>>(c_hi, c_lo, in_hi, in_lo,
                                               wout_b, nullptr, out, nullptr, 0L, 0L);
}

// Round 10
// 554.199 us; speedup vs baseline: 1.2320x; 1.1068x over previous
//
#include <hip/hip_runtime.h>
#include <hip/hip_bf16.h>

// GlobalAttention (general): B=32, T=512, S=1024, D=1024, f32 in/out.
// Split-bf16 GEMMs as K-SEGMENTED plain bf16 GEMMs (Markidis 3-term =
// [Ah|Ah|Al]x[Bh|Bl|Bh], K'=3072; GEMM4 4-seg K'=4096).
// Engine: 256x256 tile, BK=64, 8 waves (2Mx4N), 16x16x32 MFMA, LDS 128KB
// (2 buf x {A0,A1,B0,B1} 16KB halves), 1 barrier/phase, 8 phases / 2 tiles.
// A frags read IN-PHASE pre-MM (compiler counted-lgkm per use); B frags read
// ONE PHASE AHEAD (post-MM p4/p8). Stage slots (WAR-audited, round-9):
//   p1:A1(X+1) p2:B0(X+2) p3:B1(X+2) p4:A0(X+2)
//   p5:A1(X+2) p6:B0(X+3) p7:B1(X+3) p8:A0(X+3)
// ROUND-10: XCD-aware block swizzle for the BATCHED GEMMs (MODE 1/2).
// Old mapping put batch b's 8 panel-blocks on 8 different XCDs (id%8=XCD) ->
// zero in-XCD panel sharing, FETCH=393MB (vs 192MB unique), 45% HBM, and
// MfmaUtil sank to 30%. New: 1D grid 256, xcd=i&7; j=i>>3;
// batch=xcd*4+(j&3); panel=j>>2 -> each XCD owns 4 batches x 8 panels;
// A panels fetched 1x/XCD (was 4x), B 1x (was 2x); per-XCD per-tile working
// set 768KB << 4MB L2. GEMM1/4 keep 2D grid (FETCH already ideal 98.6MB).

typedef short bf16x8 __attribute__((ext_vector_type(8)));
typedef float f32x4 __attribute__((ext_vector_type(4)));
typedef unsigned short us;

#define NB 32
#define NT_ 512
#define NS 1024
#define ND 1024

__device__ inline us f2bf(float x) {
  unsigned u = __float_as_uint(x);
  u += 0x7FFFu + ((u >> 16) & 1u);
  return (us)(u >> 16);
}
__device__ inline float bf2f(us h) { return __uint_as_float(((unsigned)h) << 16); }

__device__ inline void store_split(us* __restrict__ hi, us* __restrict__ lo, size_t idx, float v) {
  us h = f2bf(v);
  hi[idx] = h;
  lo[idx] = f2bf(v - bf2f(h));
}

// ---------------- elementwise split / convert ----------------
__global__ void ga_split(const float* __restrict__ src, us* __restrict__ hi,
                         us* __restrict__ lo, long n) {
  long i0 = ((long)blockIdx.x * blockDim.x + threadIdx.x) * 4;
  long stride = (long)gridDim.x * blockDim.x * 4;
  for (long i = i0; i < n; i += stride) {
    float4 v = *reinterpret_cast<const float4*>(src + i);
    ushort4 h, l;
    h.x = f2bf(v.x); l.x = f2bf(v.x - bf2f(h.x));
    h.y = f2bf(v.y); l.y = f2bf(v.y - bf2f(h.y));
    h.z = f2bf(v.z); l.z = f2bf(v.z - bf2f(h.z));
    h.w = f2bf(v.w); l.w = f2bf(v.w - bf2f(h.w));
    *reinterpret_cast<ushort4*>(hi + i) = h;
    *reinterpret_cast<ushort4*>(lo + i) = l;
  }
}

__global__ void ga_cvt(const float* __restrict__ src, us* __restrict__ dst, long n) {
  long i0 = ((long)blockIdx.x * blockDim.x + threadIdx.x) * 4;
  long stride = (long)gridDim.x * blockDim.x * 4;
  for (long i = i0; i < n; i += stride) {
    float4 v = *reinterpret_cast<const float4*>(src + i);
    ushort4 h;
    h.x = f2bf(v.x); h.y = f2bf(v.y); h.z = f2bf(v.z); h.w = f2bf(v.w);
    *reinterpret_cast<ushort4*>(dst + i) = h;
  }
}

// ---------------- ctx transpose+split: [B][S][D] f32 -> [B][D][S] bf16 hi/lo ----------------
__global__ void ga_transpose_split(const float* __restrict__ ctx, us* __restrict__ tHi,
                                   us* __restrict__ tLo) {
  __shared__ float tile[64][65];
  int s0 = blockIdx.x << 6, d0 = blockIdx.y << 6, b = blockIdx.z;
  const float* src = ctx + (size_t)b * NS * ND;
  int tid = threadIdx.x;
#pragma unroll
  for (int i = 0; i < 16; ++i) {
    int lin = (i << 8) + tid;
    int r = lin >> 6, c = lin & 63;
    tile[r][c] = src[(size_t)(s0 + r) * ND + d0 + c];
  }
  __syncthreads();
  us* oH = tHi + (size_t)b * ND * NS;
  us* oL = tLo + (size_t)b * ND * NS;
#pragma unroll
  for (int i = 0; i < 16; ++i) {
    int lin = (i << 8) + tid;
    int dr = lin >> 6, sc = lin & 63;
    float v = tile[sc][dr];
    size_t o = (size_t)(d0 + dr) * NS + s0 + sc;
    us h = f2bf(v);
    oH[o] = h;
    oL[o] = f2bf(v - bf2f(h));
  }
}

// ---------------- row softmax, in-place f32 + split planes ----------------
__global__ __launch_bounds__(256) void ga_softmax(float* __restrict__ al,
                                                  us* __restrict__ pHi, us* __restrict__ pLo) {
  int row = blockIdx.x;  // t*32 + b
  int tid = threadIdx.x;
  float* p = al + (size_t)row * NS;
  float4 v = *reinterpret_cast<const float4*>(p + (tid << 2));
  float m = fmaxf(fmaxf(v.x, v.y), fmaxf(v.z, v.w));
#pragma unroll
  for (int off = 32; off; off >>= 1) m = fmaxf(m, __shfl_xor(m, off));
  __shared__ float rmax[4], rsum[4];
  int wv = tid >> 6, ln = tid & 63;
  if (ln == 0) rmax[wv] = m;
  __syncthreads();
  m = fmaxf(fmaxf(rmax[0], rmax[1]), fmaxf(rmax[2], rmax[3]));
  float4 e;
  e.x = __expf(v.x - m); e.y = __expf(v.y - m);
  e.z = __expf(v.z - m); e.w = __expf(v.w - m);
  float s = e.x + e.y + e.z + e.w;
#pragma unroll
  for (int off = 32; off; off >>= 1) s += __shfl_xor(s, off);
  if (ln == 0) rsum[wv] = s;
  __syncthreads();
  s = rsum[0] + rsum[1] + rsum[2] + rsum[3];
  float inv = 1.0f / s;
  e.x *= inv; e.y *= inv; e.z *= inv; e.w *= inv;
  *reinterpret_cast<float4*>(p + (tid << 2)) = e;
  int t = row >> 5, b = row & 31;
  size_t o = ((size_t)b * NT_ + t) * NS + (tid << 2);
  ushort4 h, l;
  h.x = f2bf(e.x); l.x = f2bf(e.x - bf2f(h.x));
  h.y = f2bf(e.y); l.y = f2bf(e.y - bf2f(h.y));
  h.z = f2bf(e.z); l.z = f2bf(e.z - bf2f(h.z));
  h.w = f2bf(e.w); l.w = f2bf(e.w - bf2f(h.w));
  *reinterpret_cast<ushort4*>(pHi + o) = h;
  *reinterpret_cast<ushort4*>(pLo + o) = l;
}

// ---------------- K-segmented bf16 GEMM, compiler-waited overlap engine ----------------
__device__ inline void gload16(const us* g, void* l) {
  __builtin_amdgcn_global_load_lds((const __attribute__((address_space(1))) unsigned int*)g,
                                   (__attribute__((address_space(3))) unsigned int*)l, 16, 0, 0);
}

__device__ inline f32x4 mfma16(bf16x8 a, bf16x8 b, f32x4 c) {
  return __builtin_amdgcn_mfma_f32_16x16x32_bf16(a, b, c, 0, 0, 0);
}

#define VM4 asm volatile("s_waitcnt vmcnt(4)" ::: "memory")
#define VM0 asm volatile("s_waitcnt vmcnt(0)" ::: "memory")

#define STG_A(T, H) do {                                                           \
    int s3_ = (T) >> 4;                                                            \
    const us* ga_ = (MODE == 3)                                                    \
        ? ((s3_ == 0) ? pA0 : (s3_ == 1) ? pA1 : (s3_ == 2) ? pA2 : pA3)           \
        : ((s3_ == 2) ? pA1 : pA0);                                                \
    const us* g_ = ga_ + (((T) & 15) << 6) + ((H) ? 131072 : 0) + aOff0;           \
    char* d_ = lb + (((T) & 1) << 16) + ((H) << 14) + (tid << 4);                  \
    gload16(g_, d_);                                                               \
    gload16(g_ + 65536, d_ + 8192);                                                \
  } while (0)

#define STG_B(T, H) do {                                                           \
    int s3_ = (T) >> 4;                                                            \
    const us* gb_ = (MODE == 3) ? ((s3_ >= 2) ? pB2 : pB0)                         \
                                : ((s3_ == 1) ? pB1 : pB0);                        \
    const us* g_ = gb_ + (((T) & 15) << 6) + ((H) ? (LDB << 7) : 0) + bOff0;       \
    char* d_ = lb + (((T) & 1) << 16) + 32768 + ((H) << 14) + (tid << 4);          \
    gload16(g_, d_);                                                               \
    gload16(g_ + (LDB << 6), d_ + 8192);                                           \
  } while (0)

#define RD_A(BP, ARR, QM) do {                                                     \
    const char* p_ = (BP) + aRd + ((QM) << 13);                                    \
    _Pragma("unroll") for (int m_ = 0; m_ < 4; ++m_) {                             \
      ARR[m_][0] = *(const bf16x8*)(p_ + (m_ << 11) + colx0);                      \
      ARR[m_][1] = *(const bf16x8*)(p_ + (m_ << 11) + colx1);                      \
    }                                                                              \
  } while (0)

#define RD_B(BP, ARR, QN) do {                                                     \
    const char* p_ = (BP) + bRd + ((QN) << 12);                                    \
    _Pragma("unroll") for (int n_ = 0; n_ < 2; ++n_) {                             \
      ARR[n_][0] = *(const bf16x8*)(p_ + (n_ << 11) + colx0);                      \
      ARR[n_][1] = *(const bf16x8*)(p_ + (n_ << 11) + colx1);                      \
    }                                                                              \
  } while (0)

// m-outer so the first MFMA unlocks after A[0]'s 2 reads (B pre-read earlier)
#define MM(QM, QN, AA, BB)                                                         \
  _Pragma("unroll") for (int m_ = 0; m_ < 4; ++m_)                                 \
  _Pragma("unroll") for (int ks_ = 0; ks_ < 2; ++ks_)                              \
  _Pragma("unroll") for (int n_ = 0; n_ < 2; ++n_)                                 \
    acc[(QM) * 4 + m_][(QN) * 2 + n_] =                                            \
        mfma16(AA[m_][ks_], BB[n_][ks_], acc[(QM) * 4 + m_][(QN) * 2 + n_])

#define PH(RDS, MMQ, POST) do {                                                    \
    __builtin_amdgcn_s_barrier();                                                  \
    RDS;                                                                           \
    __builtin_amdgcn_s_setprio(1);                                                 \
    MMQ;                                                                           \
    __builtin_amdgcn_s_setprio(0);                                                 \
    POST;                                                                          \
  } while (0)

// MODE 0: GEMM1 h=in*W_in^T, K'=3072 -> h planes.      grid(64,4,1)
// MODE 1: GEMM2 align=h*ctx^T, K'=3072 -> f32 align.   grid(256) XCD-swz
// MODE 2: GEMM3 c=P*ctxT^T, K'=3072 -> c planes.       grid(256) XCD-swz
// MODE 3: GEMM4 tanh(concat*W_out^T), K'=4096 -> out.  grid(64,4,1)
template <int MODE>
__global__ __launch_bounds__(512, 1) void ga_gb(
    const us* __restrict__ Ahi, const us* __restrict__ Alo,
    const us* __restrict__ A2hi, const us* __restrict__ A2lo,
    const us* __restrict__ Bhi, const us* __restrict__ Blo,
    void* __restrict__ out0, void* __restrict__ out1,
    long astride, long bstride) {
  constexpr int LDB = (MODE == 3) ? 2048 : 1024;
  constexpr int NT = (MODE == 3) ? 64 : 48;
  constexpr int NIT = NT >> 1;
  __shared__ __align__(16) char lds[131072];
  char* lb = lds;
  const int tid = threadIdx.x;
  const int lane = tid & 63;
  const int fr = lane & 15;
  const int wv = tid >> 6;
  const int wr = wv >> 2, wc = wv & 3;  // 2M x 4N waves, per-wave 128x64

  // block decode: XCD-aware for batched modes (each XCD owns 4 batches)
  int rowA, colB, bz;
  if constexpr (MODE == 1 || MODE == 2) {
    const int bi = blockIdx.x;            // 0..255, XCD ~= bi & 7
    const int j = bi >> 3;                // 0..31 within XCD
    bz = ((bi & 7) << 2) + (j & 3);       // 4 batches per XCD
    const int panel = j >> 2;             // 0..7 = 2 rowA x 4 colB
    rowA = (panel & 1) << 8;
    colB = (panel >> 1) << 8;
  } else {
    rowA = blockIdx.x << 8;
    colB = blockIdx.y << 8;
    bz = blockIdx.z;
  }

  // segment base pointers (uniform -> SGPR)
  const us* pA0 = Ahi + (size_t)bz * astride + (size_t)rowA * 1024;
  const us* pA1 = Alo + (size_t)bz * astride + (size_t)rowA * 1024;
  const us* pA2 = (MODE == 3) ? A2hi + (size_t)rowA * 1024 : nullptr;
  const us* pA3 = (MODE == 3) ? A2lo + (size_t)rowA * 1024 : nullptr;
  const us* pB0 = Bhi + (size_t)bz * bstride + (size_t)colB * LDB;
  const us* pB1 = (MODE == 3) ? nullptr : Blo + (size_t)bz * bstride + (size_t)colB * LDB;
  const us* pB2 = (MODE == 3) ? pB0 + 1024 : nullptr;

  // staging geometry (pre-swizzled global source col, linear LDS dest)
  const int arow = tid >> 3;
  const int swe = ((tid & 7) ^ (arow & 7)) << 3;
  const int aOff0 = arow * 1024 + swe;
  const int bOff0 = arow * LDB + swe;

  // frag-read geometry (swizzled)
  const int l16 = ((lane >> 4) & 3) << 4;
  const int colx0 = l16 ^ ((fr & 7) << 4);
  const int colx1 = colx0 ^ 64;
  const int aRd = (wr << 14) + (fr << 7);
  const int bRd = 32768 + ((wc >> 1) << 14) + ((wc & 1) << 13) + (fr << 7);
  const char* BUF0 = lb;
  const char* BUF1 = lb + 65536;

  bf16x8 a4[4][2], b0[2][2], b1[2][2];
  f32x4 zero = {0.f, 0.f, 0.f, 0.f};
  f32x4 acc[8][4];
#pragma unroll
  for (int i = 0; i < 8; ++i)
#pragma unroll
    for (int k = 0; k < 4; ++k) acc[i][k] = zero;

  // prologue: stage tile0 full + tile1.{B0,B1,A0} (14 loads); drain all;
  // barrier publishes; pre-read tile0's B fragments.
  STG_B(0, 0); STG_B(0, 1); STG_A(0, 0); STG_A(0, 1);
  STG_B(1, 0); STG_B(1, 1); STG_A(1, 0);
  VM0;
  __builtin_amdgcn_s_barrier();
  RD_B(BUF0, b0, 0); RD_B(BUF0, b1, 1);

  for (int i = 0; i < NIT - 1; ++i) {
    const int X = i << 1;
    PH(RD_A(BUF0, a4, 0), MM(0, 0, a4, b0), { STG_A(X + 1, 1); VM4; });
    PH(,                  MM(0, 1, a4, b1), { STG_B(X + 2, 0); VM4; });
    PH(RD_A(BUF0, a4, 1), MM(1, 0, a4, b0), { STG_B(X + 2, 1); VM4; });
    PH(,                  MM(1, 1, a4, b1),
       { RD_B(BUF1, b0, 0); RD_B(BUF1, b1, 1); STG_A(X + 2, 0); VM4; });
    PH(RD_A(BUF1, a4, 0), MM(0, 0, a4, b0), { STG_A(X + 2, 1); VM4; });
    PH(,                  MM(0, 1, a4, b1), { STG_B(X + 3, 0); VM4; });
    PH(RD_A(BUF1, a4, 1), MM(1, 0, a4, b0), { STG_B(X + 3, 1); VM4; });
    PH(,                  MM(1, 1, a4, b1),
       { RD_B(BUF0, b0, 0); RD_B(BUF0, b1, 1); STG_A(X + 3, 0); VM4; });
  }
  // peeled last pair (tiles NT-2 in BUF0, NT-1 in BUF1): stage only
  // A1(NT-1)@p1; VM0@p3-post drains it, barrier_p4 publishes before the
  // p4 pre-reads and the p5/p7 A reads of BUF1.
  PH(RD_A(BUF0, a4, 0), MM(0, 0, a4, b0), { STG_A(NT - 1, 1); VM4; });
  PH(,                  MM(0, 1, a4, b1), {});
  PH(RD_A(BUF0, a4, 1), MM(1, 0, a4, b0), { VM0; });
  PH(,                  MM(1, 1, a4, b1),
     { RD_B(BUF1, b0, 0); RD_B(BUF1, b1, 1); });
  PH(RD_A(BUF1, a4, 0), MM(0, 0, a4, b0), {});
  PH(,                  MM(0, 1, a4, b1), {});
  PH(RD_A(BUF1, a4, 1), MM(1, 0, a4, b0), {});
  PH(,                  MM(1, 1, a4, b1), {});

  // epilogue: C/D layout col=lane&15, row=(lane>>4)*4+j
#pragma unroll
  for (int mf = 0; mf < 8; ++mf)
#pragma unroll
    for (int nf = 0; nf < 4; ++nf)
#pragma unroll
      for (int j = 0; j < 4; ++j) {
        int r = rowA + (wr << 7) + (mf << 4) + (((lane >> 4) & 3) << 2) + j;
        int c = colB + (wc << 6) + (nf << 4) + fr;
        float v = acc[mf][nf][j];
        if constexpr (MODE == 0) {
          store_split((us*)out0, (us*)out1, (size_t)r * 1024 + c, v);
        } else if constexpr (MODE == 1) {
          ((float*)out0)[((size_t)r * NB + bz) * NS + c] = v;  // align[t][b][s]
        } else if constexpr (MODE == 2) {
          store_split((us*)out0, (us*)out1, ((size_t)bz * 512 + r) * 1024 + c, v);
        } else {
          int bb = r >> 9, tt2 = r & 511;
          ((float*)out0)[((size_t)tt2 * NB + bb) * ND + c] = tanhf(v);  // attn[t][b][d]
        }
      }
}

// ---------------- launch ----------------
extern "C" void kernel_launch(void* const* d_in, const int* in_sizes, int n_in,
                              void* d_out, int out_size, void* d_ws, size_t ws_size,
                              hipStream_t stream) {
  (void)in_sizes; (void)n_in; (void)out_size; (void)ws_size;
  const float* inp = (const float*)d_in[0];   // [32][512][1024]
  const float* ctx = (const float*)d_in[1];   // [32][1024][1024]
  const float* Win = (const float*)d_in[2];   // [1024][1024] (e,d)
  const float* Wout = (const float*)d_in[3];  // [1024][2048] (d,f)
  float* out = (float*)d_out;

  char* w = (char*)d_ws;
  us* ctx_hi  = (us*)(w + 0);
  us* c_hi    = (us*)(w + 0);
  us* c_lo    = (us*)(w + 33554432);
  us* ctx_lo  = (us*)(w + 67108864);
  us* p_hi    = (us*)(w + 67108864);
  us* p_lo    = (us*)(w + 100663296);
  us* in_hi   = (us*)(w + 134217728);
  us* in_lo   = (us*)(w + 167772160);
  us* h_hi    = (us*)(w + 201326592);
  us* h_lo    = (us*)(w + 234881024);
  us* ctxT_lo = (us*)(w + 201326592);  // reuses h region after GEMM2
  us* win_hi  = (us*)(w + 268435456);
  us* win_lo  = (us*)(w + 270532608);
  us* wout_b  = (us*)(w + 272629760);

  us* ctxT_hi = (us*)d_out;            // attn region as scratch until GEMM4
  float* alignOut = out + 16777216;    // second half of d_out

  ga_split<<<2048, 256, 0, stream>>>(inp, in_hi, in_lo, 16777216L);
  ga_split<<<2048, 256, 0, stream>>>(ctx, ctx_hi, ctx_lo, 33554432L);
  ga_split<<<512, 256, 0, stream>>>(Win, win_hi, win_lo, 1048576L);
  ga_cvt<<<512, 256, 0, stream>>>(Wout, wout_b, 2097152L);

  // GEMM1: h = in @ W_in^T   (M=16384, N=1024, K'=3072)
  ga_gb<0><<<dim3(64, 4, 1), 512, 0, stream>>>(in_hi, in_lo, nullptr, nullptr,
                                               win_hi, win_lo, h_hi, h_lo, 0L, 0L);
  // GEMM2: align = h @ ctx^T (batched 32; M=512, N=1024, K'=3072) [XCD swz]
  ga_gb<1><<<dim3(256, 1, 1), 512, 0, stream>>>(h_hi, h_lo, nullptr, nullptr,
                                                ctx_hi, ctx_lo, alignOut, nullptr,
                                                524288L, 1048576L);
  // ctx transpose+split (overwrites h region -> must follow GEMM2; stream-ordered)
  ga_transpose_split<<<dim3(16, 16, 32), 256, 0, stream>>>(ctx, ctxT_hi, ctxT_lo);
  // softmax in-place + P split planes
  ga_softmax<<<16384, 256, 0, stream>>>(alignOut, p_hi, p_lo);
  // GEMM3: c = P @ ctx (via ctxT planes; batched; M=512, N=1024, K'=3072) [XCD swz]
  ga_gb<2><<<dim3(256, 1, 1), 512, 0, stream>>>(p_hi, p_lo, nullptr, nullptr,
                                                ctxT_hi, ctxT_lo, c_hi, c_lo,
                                                524288L, 1048576L);
  // GEMM4: attn = tanh(concat[c,in] @ W_out^T) (M=16384, N=1024, K'=4096)
  ga_gb<3><<<dim3(64, 4, 1), 512, 0, stream>>>(c_hi, c_lo, in_hi, in_lo,
                                               wout_b, nullptr, out, nullptr, 0L, 0L);
}